// Round 18
// baseline (308.404 us; speedup 1.0000x reference)
//
#include <hip/hip_runtime.h>
#include <hip/hip_bf16.h>

// GATConv, N=8192, F_in=F_out=128, dense 0/1 adjacency (int32).
// Rank-1 logits: e_ij = LeakyReLU(es_i + ed_j). exp safe in f32 -> additive
// softmax partials.
//
// R18: decisive ILP experiment on the proven R15 k2 (105us, barrier-free).
// R16 ablation showed FULL = LOADS + P + MFMA additively (dependency-serial).
// Each wave now runs TWO independent j-streams (its 1024-j slice split in
// half), ping-ponged: stream X's loads fly while stream Y computes. Both
// streams accumulate into the SAME acc (j = reduction axis) -> only phase
// regs duplicate. No barriers, no LDS in loop, R15 epilogue unchanged.
//   (a) latency-serialization hypothesis -> k2 ~60-70us
//   (b) issue-throughput-wall hypothesis -> k2 unchanged (~105)

typedef __bf16 bf16_t;
typedef bf16_t bf16x8 __attribute__((ext_vector_type(8)));
typedef float  f32x4  __attribute__((ext_vector_type(4)));
typedef int    i32x4  __attribute__((ext_vector_type(4)));

#define NN 8192
#define DD 128

// ---- kF: fused k1 (blocks 0..255) + kA pack (blocks 256..4351) ----
__global__ __launch_bounds__(512) void kF_pre(const float* __restrict__ X,
                                              const float* __restrict__ W,
                                              const float* __restrict__ a_src,
                                              const float* __restrict__ a_dst,
                                              const int* __restrict__ A,
                                              unsigned* __restrict__ bits,
                                              float* __restrict__ es,
                                              float* __restrict__ edv,
                                              bf16_t* __restrict__ VB) {
  __shared__ float Wl[DD * DD];
  __shared__ bf16_t Tl[DD][40];
  const int t = threadIdx.x;

  if (blockIdx.x >= 256) {
    const int w = (blockIdx.x - 256) * 512 + t;
    const i32x4* p = (const i32x4*)(A + (size_t)w * 32);
    i32x4 v[8];
    #pragma unroll
    for (int q = 0; q < 8; ++q) v[q] = p[q];
    unsigned m = 0;
    #pragma unroll
    for (int q = 0; q < 8; ++q) {
      #pragma unroll
      for (int e = 0; e < 4; ++e) m |= ((unsigned)v[q][e]) << (q * 4 + e);
    }
    const int row = w >> 8;
    const int c0 = (w & 255) << 5;
    if (row >= c0 && row < c0 + 32) m |= 1u << (row - c0);
    bits[w] = m;
    return;
  }

  const int rb = blockIdx.x << 5;

  if (t < 256) {
    const int k = t & 127;
    const float* av = (t < 128) ? a_src : a_dst;
    const f32x4* wrow = (const f32x4*)(W + k * DD);
    float s = 0.f;
    #pragma unroll
    for (int c4 = 0; c4 < 32; ++c4) {
      const f32x4 wv = wrow[c4];
      const f32x4 avv = *(const f32x4*)(av + c4 * 4);
      s += wv[0] * avv[0] + wv[1] * avv[1] + wv[2] * avv[2] + wv[3] * avv[3];
    }
    Wl[t] = s;
  }
  if (t < 64) Wl[256 + t] = 0.f;
  __syncthreads();

  {
    const int r = t >> 4, part = t & 15;
    const f32x4* xrow = (const f32x4*)(X + (size_t)(rb + r) * DD + part * 8);
    float s = 0.f, d = 0.f;
    #pragma unroll
    for (int q = 0; q < 2; ++q) {
      const f32x4 xv = xrow[q];
      const f32x4 sv = *(const f32x4*)(Wl + part * 8 + q * 4);
      const f32x4 dv = *(const f32x4*)(Wl + 128 + part * 8 + q * 4);
      s += xv[0] * sv[0] + xv[1] * sv[1] + xv[2] * sv[2] + xv[3] * sv[3];
      d += xv[0] * dv[0] + xv[1] * dv[1] + xv[2] * dv[2] + xv[3] * dv[3];
    }
    atomicAdd(&Wl[256 + r], s);
    atomicAdd(&Wl[288 + r], d);
  }
  __syncthreads();
  if (t < 32) {
    es[rb + t] = Wl[256 + t];
  } else if (t < 64) {
    edv[rb + t - 32] = Wl[288 + t - 32];
  }
  __syncthreads();

  for (int idx = t; idx < DD * DD; idx += 512) Wl[idx] = W[idx];
  __syncthreads();

  const int c = t & 127;
  const int r0 = t >> 7;
  for (int rr = 0; rr < 8; ++rr) {
    const int r = (rr << 2) + r0;
    const f32x4* xrow = (const f32x4*)(X + (size_t)(rb + r) * DD);
    float acc = 0.f;
    #pragma unroll
    for (int k4 = 0; k4 < 32; ++k4) {
      const f32x4 xv = xrow[k4];
      acc += xv[0] * Wl[(k4 * 4 + 0) * DD + c] + xv[1] * Wl[(k4 * 4 + 1) * DD + c] +
             xv[2] * Wl[(k4 * 4 + 2) * DD + c] + xv[3] * Wl[(k4 * 4 + 3) * DD + c];
    }
    Tl[c][r] = (bf16_t)acc;
  }
  __syncthreads();

  // VB[((jb*8 + cb)*64 + lane)*8 + e] = H[jb*32 + (lane>>4)*8 + e][cb*16 + (lane&15)]
  {
    const int cb = t >> 6;
    const int lane = t & 63;
    const int col = (cb << 4) + (lane & 15);
    const int rloc = (lane >> 4) << 3;
    const bf16x8 u = *(const bf16x8*)&Tl[col][rloc];
    *(bf16x8*)(VB + ((((size_t)(rb >> 5) << 3) + cb) * 64 + lane) * 8) = u;
  }
}

// ---- K2: 2-stream masked GEMM. 512 blocks (2/CU) x 512 thr (8 waves). ----
// Block = 32 rows x 64-col half x full j. Wave ws: slice [ws*1024,+1024)
// split into stream A = first 512 j, stream B = last 512 j; ping-pong.
__global__ __launch_bounds__(512, 4) void k2_gat(const unsigned* __restrict__ bits,
                                                 const float* __restrict__ es,
                                                 const float* __restrict__ edv,
                                                 const bf16_t* __restrict__ VB,
                                                 float* __restrict__ out) {
  __shared__ float numL[32 * 64];  // 8 KB
  __shared__ float denL[32];
  const int t = threadIdx.x;
  const int lane = t & 63, ws = t >> 6;
  const int l16 = lane & 15, lk = lane >> 4;
  const int rt = blockIdx.x >> 1;
  const int ch = blockIdx.x & 1;
  const int rb = rt << 5;

  for (int idx = t; idx < 32 * 64; idx += 512) numL[idx] = 0.f;
  if (t < 32) denL[t] = 0.f;

  const int r0 = rb + l16;
  const int r1 = r0 + 16;
  const float es0 = es[r0];
  const float es1 = es[r1];

  // stream A: j in [ws*1024, +512) = steps 0..15 ; stream B: +512
  const unsigned* pB0A = bits + (size_t)r0 * 256 + (ws << 5);
  const unsigned* pB1A = bits + (size_t)r1 * 256 + (ws << 5);
  const unsigned* pB0B = pB0A + 16;
  const unsigned* pB1B = pB1A + 16;
  const float* pedA = edv + (ws << 10) + (lk << 3);
  const float* pedB = pedA + 512;
  const bf16_t* pVA = VB + (((size_t)(ws << 5) * 8 + (ch << 2)) * 64 + lane) * 8;
  const bf16_t* pVB_ = pVA + (size_t)16 * 4096;

  f32x4 acc0[4], acc1[4];  // shared by both streams (j = reduction axis)
  #pragma unroll
  for (int cf = 0; cf < 4; ++cf) {
    acc0[cf] = f32x4{0.f, 0.f, 0.f, 0.f};
    acc1[cf] = f32x4{0.f, 0.f, 0.f, 0.f};
  }
  float dsum0 = 0.f, dsum1 = 0.f;

  // stream phase registers
  unsigned aB0, aB1, bB0, bB1;
  f32x4 aE0, aE1, bE0, bE1;
  bf16x8 aV0, aV1, aV2, aV3, bV0, bV1, bV2, bV3;

  auto LOAD = [&](int s, const unsigned* q0, const unsigned* q1, const float* pe,
                  const bf16_t* pv, unsigned& x0, unsigned& x1, f32x4& e0, f32x4& e1,
                  bf16x8& v0, bf16x8& v1, bf16x8& v2, bf16x8& v3) {
    x0 = q0[s];
    x1 = q1[s];
    const float* p = pe + (s << 5);
    e0 = *(const f32x4*)p;
    e1 = *(const f32x4*)(p + 4);
    const bf16_t* v = pv + (size_t)s * 4096;
    v0 = *(const bf16x8*)v;
    v1 = *(const bf16x8*)(v + 512);
    v2 = *(const bf16x8*)(v + 1024);
    v3 = *(const bf16x8*)(v + 1536);
  };

  auto COMP = [&](unsigned x0, unsigned x1, f32x4 e0, f32x4 e1, bf16x8 v0, bf16x8 v1,
                  bf16x8 v2, bf16x8 v3) {
    const unsigned m0 = x0 >> (lk << 3);
    const unsigned m1 = x1 >> (lk << 3);
    bf16x8 pa0, pa1;
    float p0s = 0.f, p1s = 0.f;
    #pragma unroll
    for (int e = 0; e < 8; ++e) {
      const float edq = (e < 4) ? e0[e] : e1[e - 4];
      float x0f = es0 + edq;
      x0f = fmaxf(x0f, 0.2f * x0f);
      float x1f = es1 + edq;
      x1f = fmaxf(x1f, 0.2f * x1f);
      const float p0 = ((m0 >> e) & 1u) ? __expf(x0f) : 0.f;
      const float p1 = ((m1 >> e) & 1u) ? __expf(x1f) : 0.f;
      p0s += p0;
      p1s += p1;
      pa0[e] = (bf16_t)p0;
      pa1[e] = (bf16_t)p1;
    }
    dsum0 += p0s;
    dsum1 += p1s;
    acc0[0] = __builtin_amdgcn_mfma_f32_16x16x32_bf16(pa0, v0, acc0[0], 0, 0, 0);
    acc1[0] = __builtin_amdgcn_mfma_f32_16x16x32_bf16(pa1, v0, acc1[0], 0, 0, 0);
    acc0[1] = __builtin_amdgcn_mfma_f32_16x16x32_bf16(pa0, v1, acc0[1], 0, 0, 0);
    acc1[1] = __builtin_amdgcn_mfma_f32_16x16x32_bf16(pa1, v1, acc1[1], 0, 0, 0);
    acc0[2] = __builtin_amdgcn_mfma_f32_16x16x32_bf16(pa0, v2, acc0[2], 0, 0, 0);
    acc1[2] = __builtin_amdgcn_mfma_f32_16x16x32_bf16(pa1, v2, acc1[2], 0, 0, 0);
    acc0[3] = __builtin_amdgcn_mfma_f32_16x16x32_bf16(pa0, v3, acc0[3], 0, 0, 0);
    acc1[3] = __builtin_amdgcn_mfma_f32_16x16x32_bf16(pa1, v3, acc1[3], 0, 0, 0);
  };

  // prologue: both streams' step-0 loads in flight
  LOAD(0, pB0A, pB1A, pedA, pVA, aB0, aB1, aE0, aE1, aV0, aV1, aV2, aV3);
  LOAD(0, pB0B, pB1B, pedB, pVB_, bB0, bB1, bE0, bE1, bV0, bV1, bV2, bV3);

  #pragma unroll 1
  for (int s = 0; s < 16; ++s) {
    // compute stream A step s (loads issued >= 1 full B-phase ago)
    COMP(aB0, aB1, aE0, aE1, aV0, aV1, aV2, aV3);
    if (s + 1 < 16)
      LOAD(s + 1, pB0A, pB1A, pedA, pVA, aB0, aB1, aE0, aE1, aV0, aV1, aV2, aV3);
    // compute stream B step s
    COMP(bB0, bB1, bE0, bE1, bV0, bV1, bV2, bV3);
    if (s + 1 < 16)
      LOAD(s + 1, pB0B, pB1B, pedB, pVB_, bB0, bB1, bE0, bE1, bV0, bV1, bV2, bV3);
  }

  // ---- epilogue: LDS merge across the 8 j-slice waves (R15, validated) ----
  dsum0 += __shfl_xor(dsum0, 16, 64);
  dsum0 += __shfl_xor(dsum0, 32, 64);
  dsum1 += __shfl_xor(dsum1, 16, 64);
  dsum1 += __shfl_xor(dsum1, 32, 64);
  __syncthreads();
  if (lane < 16) {
    atomicAdd(&denL[l16], dsum0);
    atomicAdd(&denL[16 + l16], dsum1);
  }
  #pragma unroll
  for (int cf = 0; cf < 4; ++cf) {
    #pragma unroll
    for (int r = 0; r < 4; ++r) {
      // C/D: row = (lane>>4)*4 + reg, col = lane&15 (validated layout)
      atomicAdd(&numL[((lk << 2) + r) * 64 + (cf << 4) + l16], acc0[cf][r]);
      atomicAdd(&numL[(16 + (lk << 2) + r) * 64 + (cf << 4) + l16], acc1[cf][r]);
    }
  }
  __syncthreads();

  {
    const int row = t >> 4;        // 0..31
    const int c0 = (t & 15) << 2;  // 0..60
    const float rd = 1.f / denL[row];
    f32x4 o;
    #pragma unroll
    for (int q = 0; q < 4; ++q) {
      float v = numL[row * 64 + c0 + q] * rd;
      o[q] = v > 0.f ? v : (__expf(v) - 1.f);
    }
    *(f32x4*)(out + (size_t)(rb + row) * DD + (ch << 6) + c0) = o;
  }
}

extern "C" void kernel_launch(void* const* d_in, const int* in_sizes, int n_in,
                              void* d_out, int out_size, void* d_ws, size_t ws_size,
                              hipStream_t stream) {
  const float* X = (const float*)d_in[0];
  const int* A = (const int*)d_in[1];
  const float* W = (const float*)d_in[2];
  const float* a_src = (const float*)d_in[3];
  const float* a_dst = (const float*)d_in[4];
  float* out = (float*)d_out;

  char* w = (char*)d_ws;
  unsigned* bitsv = (unsigned*)(w + 0);  // 8 MB
  bf16_t* VB = (bf16_t*)(w + 8388608);   // 2 MB frag-major H
  float* es = (float*)(w + 10485760);    // 32 KB
  float* edv = (float*)(w + 10518528);   // 32 KB  (total ~10.1 MB)

  hipLaunchKernelGGL(kF_pre, dim3(256 + 4096), dim3(512), 0, stream, X, W, a_src,
                     a_dst, A, bitsv, es, edv, VB);
  hipLaunchKernelGGL(k2_gat, dim3(512), dim3(512), 0, stream, bitsv, es, edv, VB, out);
}